// Round 1
// baseline (516.033 us; speedup 1.0000x reference)
//
#include <hip/hip_runtime.h>
#include <math.h>

#define NSEG 126

// ---------------------------------------------------------------------------
// prep kernels: bucket the (rr, cc, seg) point list by column (cc)
// ---------------------------------------------------------------------------
__global__ void prep_zero(float* acc, int* counts) {
    int i = blockIdx.x * 256 + threadIdx.x;      // grid 3 -> 768 threads
    if (i < NSEG * 4) acc[i] = 0.f;
    int j = i - 512;
    if (j >= 0 && j < 256) counts[j] = 0;
}

__global__ void prep_hist(const int* __restrict__ cc, int n, int* counts) {
    int i = blockIdx.x * 256 + threadIdx.x;
    if (i < n) atomicAdd(&counts[cc[i]], 1);
}

__global__ void prep_scan(const int* __restrict__ counts, int* starts, int* cursor) {
    int lane = threadIdx.x;                      // 64 threads
    int4 c = reinterpret_cast<const int4*>(counts)[lane];
    int lsum = c.x + c.y + c.z + c.w;
    int pre = lsum;
    for (int off = 1; off < 64; off <<= 1) {
        int v = __shfl_up(pre, off);
        if (lane >= off) pre += v;
    }
    int excl = pre - lsum;
    int o0 = excl, o1 = o0 + c.x, o2 = o1 + c.y, o3 = o2 + c.z;
    int4 outv = make_int4(o0, o1, o2, o3);
    reinterpret_cast<int4*>(starts)[lane] = outv;
    reinterpret_cast<int4*>(cursor)[lane] = outv;
    if (lane == 63) starts[256] = o3 + c.w;
}

__global__ void prep_scatter(const int* __restrict__ rr, const int* __restrict__ cc,
                             const int* __restrict__ seg, int n, int* cursor,
                             int* b_rr, int* b_seg) {
    int i = blockIdx.x * 256 + threadIdx.x;
    if (i < n) {
        int pos = atomicAdd(&cursor[cc[i]], 1);
        b_rr[pos]  = rr[i];
        b_seg[pos] = seg[i];
    }
}

// ---------------------------------------------------------------------------
// Row-pass FFT: for each image row x, G[img][x][v] = FFT_y(img[x, :])
// block = 256 threads = 4 waves, one 256-pt Stockham FFT per wave.
// ---------------------------------------------------------------------------
__global__ __launch_bounds__(256) void rowfft_kernel(
    const float* __restrict__ inp, const float* __restrict__ tgt,
    float2* __restrict__ G, int pair_base)
{
    __shared__ float2 bufA[4][256];
    __shared__ float2 bufB[4][256];
    int bid  = blockIdx.x;
    int limg = bid >> 6;                          // local image (chunk-relative)
    int wv   = threadIdx.x >> 6;
    int lane = threadIdx.x & 63;
    int row  = ((bid & 63) << 2) + wv;
    int t    = limg & 1;
    int p    = pair_base + (limg >> 1);
    const float* src = (t == 0 ? inp : tgt) + (((size_t)p) << 16) + ((size_t)row << 8);

    float4 v = reinterpret_cast<const float4*>(src)[lane];
    bufA[wv][lane * 4 + 0] = make_float2(v.x, 0.f);
    bufA[wv][lane * 4 + 1] = make_float2(v.y, 0.f);
    bufA[wv][lane * 4 + 2] = make_float2(v.z, 0.f);
    bufA[wv][lane * 4 + 3] = make_float2(v.w, 0.f);
    __syncthreads();

    float2* a = bufA[wv];
    float2* b = bufB[wv];
    #pragma unroll
    for (int s = 0; s < 8; s++) {
        int L = 1 << s;
        #pragma unroll
        for (int i = 0; i < 2; i++) {
            int bf = lane + (i << 6);             // butterfly id 0..127
            int r  = bf & (L - 1);
            int q  = bf >> s;
            float2 c0 = a[q * L + r];
            float2 c1 = a[q * L + r + 128];
            float ang = -3.14159265358979f * (float)r / (float)L;
            float wi, wr;
            __sincosf(ang, &wi, &wr);
            float2 w1 = make_float2(wr * c1.x - wi * c1.y, wr * c1.y + wi * c1.x);
            b[(q << (s + 1)) + r]     = make_float2(c0.x + w1.x, c0.y + w1.y);
            b[(q << (s + 1)) + r + L] = make_float2(c0.x - w1.x, c0.y - w1.y);
        }
        __syncthreads();
        float2* tp = a; a = b; b = tp;
    }
    // result in bufA[wv] (8 swaps -> back to A)
    float2* dst = G + (((size_t)limg) << 16) + ((size_t)row << 8);
    float4* dst4 = reinterpret_cast<float4*>(dst);
    const float4* a4 = reinterpret_cast<const float4*>(a);
    dst4[lane * 2]     = a4[lane * 2];
    dst4[lane * 2 + 1] = a4[lane * 2 + 1];
}

// ---------------------------------------------------------------------------
// Column-pass FFT fused with gather+segment-accumulate.
// block = 1024 threads = 16 waves. Each block: one image PAIR, 64 columns
// (8 sub-iters x 8 columns x 2 images -> 16 column-FFTs per sub-iter).
// ---------------------------------------------------------------------------
__global__ __launch_bounds__(1024) void colfft_gather_kernel(
    const float2* __restrict__ G, const int* __restrict__ starts,
    const int* __restrict__ b_rr, const int* __restrict__ b_seg,
    float* __restrict__ acc)
{
    __shared__ float2 bufA[16][256];
    __shared__ float2 bufB[16][256];
    __shared__ float accl[NSEG * 4];
    int tid = threadIdx.x;
    for (int i = tid; i < NSEG * 4; i += 1024) accl[i] = 0.f;

    int plocal = blockIdx.x >> 2;
    int cg     = blockIdx.x & 3;
    int wv     = tid >> 6;
    int lane   = tid & 63;
    const float2* Gp = G + (((size_t)plocal) << 17);   // 2 images * 65536

    for (int sub = 0; sub < 8; sub++) {
        int colbase = (cg << 6) + (sub << 3);
        __syncthreads();                              // bufA free from prev gather
        // cooperative tile load: 2 images x 256 x-values x 8 cols
        #pragma unroll
        for (int i = 0; i < 4; i++) {
            int idx = tid + (i << 10);                // 0..4095
            int c = idx & 7;
            int x = (idx >> 3) & 255;
            int t = idx >> 11;
            bufA[t * 8 + c][x] = Gp[((size_t)t << 16) + (x << 8) + colbase + c];
        }
        __syncthreads();

        float2* a = bufA[wv];
        float2* b = bufB[wv];
        #pragma unroll
        for (int s = 0; s < 8; s++) {
            int L = 1 << s;
            #pragma unroll
            for (int i = 0; i < 2; i++) {
                int bf = lane + (i << 6);
                int r  = bf & (L - 1);
                int q  = bf >> s;
                float2 c0 = a[q * L + r];
                float2 c1 = a[q * L + r + 128];
                float ang = -3.14159265358979f * (float)r / (float)L;
                float wi, wr;
                __sincosf(ang, &wi, &wr);
                float2 w1 = make_float2(wr * c1.x - wi * c1.y, wr * c1.y + wi * c1.x);
                b[(q << (s + 1)) + r]     = make_float2(c0.x + w1.x, c0.y + w1.y);
                b[(q << (s + 1)) + r + L] = make_float2(c0.x - w1.x, c0.y - w1.y);
            }
            __syncthreads();
            float2* tp = a; a = b; b = tp;
        }
        // result in bufA[w]: F[u, col] for wave w's column. Gather points.
        for (int c = 0; c < 8; c++) {
            int col = colbase + c;
            int s0 = starts[col], s1 = starts[col + 1];
            for (int e = s0 + tid; e < s1; e += 1024) {
                int rr = b_rr[e];
                int sg = b_seg[e];
                float2 f1 = bufA[c][rr];         // input-image F
                float2 f2 = bufA[8 + c][rr];     // target-image F
                atomicAdd(&accl[sg * 4 + 0], f1.x * f2.x + f1.y * f2.y);
                atomicAdd(&accl[sg * 4 + 1], f1.y * f2.x - f1.x * f2.y);
                atomicAdd(&accl[sg * 4 + 2], f1.x * f1.x + f1.y * f1.y);
                atomicAdd(&accl[sg * 4 + 3], f2.x * f2.x + f2.y * f2.y);
            }
        }
    }
    __syncthreads();
    for (int i = tid; i < NSEG * 4; i += 1024) {
        float v = accl[i];
        if (v != 0.f) atomicAdd(&acc[i], v);
    }
}

// ---------------------------------------------------------------------------
// Final: curve = [1, |cross_s| / sqrt(pw1_s * pw2_s)], out = npairs * dot(curve, w)
// ---------------------------------------------------------------------------
__global__ void final_kernel(const float* __restrict__ acc, const float* __restrict__ w,
                             float* __restrict__ out, float scale) {
    int lane = threadIdx.x;                       // 64 threads
    float val = 0.f;
    for (int s = lane; s < NSEG; s += 64) {
        float cr = acc[s * 4 + 0], ci = acc[s * 4 + 1];
        float p1 = acc[s * 4 + 2], p2 = acc[s * 4 + 3];
        float num = sqrtf(cr * cr + ci * ci);
        float den = p1 * p2;
        float curve = den > 0.f ? num * rsqrtf(den) : 0.f;
        val += curve * w[s + 1];
    }
    if (lane == 0) val += w[0];                   // curve[0] = 1
    for (int off = 32; off > 0; off >>= 1) val += __shfl_down(val, off);
    if (lane == 0) out[0] = scale * val;
}

// ---------------------------------------------------------------------------
extern "C" void kernel_launch(void* const* d_in, const int* in_sizes, int n_in,
                              void* d_out, int out_size, void* d_ws, size_t ws_size,
                              hipStream_t stream)
{
    const float* inp = (const float*)d_in[0];
    const float* tgt = (const float*)d_in[1];
    const float* wts = (const float*)d_in[2];
    const int*   rr  = (const int*)d_in[3];
    const int*   cc  = (const int*)d_in[4];
    const int*   sg  = (const int*)d_in[5];
    int npts   = in_sizes[3];
    int npairs = in_sizes[0] >> 16;               // B*C = 192 (65536 px/img)

    char* ws = (char*)d_ws;
    float* acc    = (float*)(ws + 0);             // 504 floats
    int*   counts = (int*)(ws + 2048);            // 256 ints
    int*   starts = (int*)(ws + 3072);            // 257 ints
    int*   cursor = (int*)(ws + 5120);            // 256 ints
    int*   b_rr   = (int*)(ws + 6144);
    int*   b_seg  = b_rr + npts;
    size_t goff = 6144 + (size_t)2 * npts * 4;
    goff = (goff + 255) & ~(size_t)255;
    float2* G = (float2*)(ws + goff);

    size_t per_pair = (size_t)2 * 65536 * sizeof(float2);  // 1 MiB per image pair
    int maxchunk = (int)((ws_size > goff ? (ws_size - goff) : 0) / per_pair);
    if (maxchunk < 1) maxchunk = 1;
    if (maxchunk > npairs) maxchunk = npairs;

    prep_zero<<<3, 256, 0, stream>>>(acc, counts);
    prep_hist<<<(npts + 255) / 256, 256, 0, stream>>>(cc, npts, counts);
    prep_scan<<<1, 64, 0, stream>>>(counts, starts, cursor);
    prep_scatter<<<(npts + 255) / 256, 256, 0, stream>>>(rr, cc, sg, npts, cursor, b_rr, b_seg);

    for (int pb = 0; pb < npairs; pb += maxchunk) {
        int cp = npairs - pb < maxchunk ? npairs - pb : maxchunk;
        rowfft_kernel<<<cp * 2 * 64, 256, 0, stream>>>(inp, tgt, G, pb);
        colfft_gather_kernel<<<cp * 4, 1024, 0, stream>>>(G, starts, b_rr, b_seg, acc);
    }

    final_kernel<<<1, 64, 0, stream>>>(acc, wts, (float*)d_out, (float)npairs);
}

// Round 2
// 285.754 us; speedup vs baseline: 1.8059x; 1.8059x over previous
//
#include <hip/hip_runtime.h>
#include <math.h>

#define NSEG 126

__device__ __forceinline__ unsigned bitrev8(unsigned v) { return __brev(v) >> 24; }

// ---------------------------------------------------------------------------
// Register-resident 256-point DIF FFT across one wave (64 lanes x 4 float2).
// Element e = i*64 + lane. On exit x[i] holds X[bitrev8(e)].
// ---------------------------------------------------------------------------
__device__ __forceinline__ void fft256(float2 x[4], int lane) {
    const float PI = 3.14159265358979323846f;
    // Stage M=256: pairs (i, i+2), twiddle j = i*64+lane
    {
        float s, c;
        __sincosf(-PI * (float)lane * (1.0f / 128.0f), &s, &c);
        float2 w0 = make_float2(c, s);       // j = lane
        float2 w1 = make_float2(s, -c);      // j = lane+64 : w0 * (-i)
        float2 u, t, d;
        u = x[0]; t = x[2];
        x[0] = make_float2(u.x + t.x, u.y + t.y);
        d = make_float2(u.x - t.x, u.y - t.y);
        x[2] = make_float2(d.x * w0.x - d.y * w0.y, d.x * w0.y + d.y * w0.x);
        u = x[1]; t = x[3];
        x[1] = make_float2(u.x + t.x, u.y + t.y);
        d = make_float2(u.x - t.x, u.y - t.y);
        x[3] = make_float2(d.x * w1.x - d.y * w1.y, d.x * w1.y + d.y * w1.x);
    }
    // Stage M=128: pairs (0,1) and (2,3), twiddle j = lane (same for both)
    {
        float s, c;
        __sincosf(-PI * (float)lane * (1.0f / 64.0f), &s, &c);
        float2 w = make_float2(c, s);
        float2 u, t, d;
        u = x[0]; t = x[1];
        x[0] = make_float2(u.x + t.x, u.y + t.y);
        d = make_float2(u.x - t.x, u.y - t.y);
        x[1] = make_float2(d.x * w.x - d.y * w.y, d.x * w.y + d.y * w.x);
        u = x[2]; t = x[3];
        x[2] = make_float2(u.x + t.x, u.y + t.y);
        d = make_float2(u.x - t.x, u.y - t.y);
        x[3] = make_float2(d.x * w.x - d.y * w.y, d.x * w.y + d.y * w.x);
    }
    // Stages M=64..2 : cross-lane via shfl_xor(h), h = 32..1
    #pragma unroll
    for (int hbit = 5; hbit >= 0; hbit--) {
        int h = 1 << hbit;
        int j = lane & (h - 1);
        float s, c;
        __sincosf(-PI * (float)j / (float)h, &s, &c);
        bool up = (lane & h) != 0;
        #pragma unroll
        for (int i = 0; i < 4; i++) {
            float px = __shfl_xor(x[i].x, h);
            float py = __shfl_xor(x[i].y, h);
            if (up) {
                float dx = px - x[i].x, dy = py - x[i].y;
                x[i] = make_float2(dx * c - dy * s, dx * s + dy * c);
            } else {
                x[i] = make_float2(x[i].x + px, x[i].y + py);
            }
        }
    }
}

// ---------------------------------------------------------------------------
// prep: filter to the cc>=128 half-plane, bucket by stored column index
// j' = bitrev8(cc) >> 1 (in [0,128)), store bit-reversed row position.
// ---------------------------------------------------------------------------
__global__ void prep_zero(float* acc, int* counts) {
    int i = blockIdx.x * 256 + threadIdx.x;      // grid 2 -> 512 threads
    if (i < NSEG * 3) acc[i] = 0.f;
    if (i < 128) counts[i] = 0;
}

__device__ __forceinline__ bool keep_point(int r, int c) {
    return (c > 128) || (c == 128 && r > 128);
}

__global__ void prep_hist(const int* __restrict__ rr, const int* __restrict__ cc,
                          int n, int* counts) {
    int i = blockIdx.x * 256 + threadIdx.x;
    if (i < n) {
        int c = cc[i], r = rr[i];
        if (keep_point(r, c)) {
            int j = (int)(bitrev8((unsigned)c) >> 1);
            atomicAdd(&counts[j], 1);
        }
    }
}

__global__ void prep_scan(const int* __restrict__ counts, int* starts, int* cursor) {
    int lane = threadIdx.x;                      // 64 threads, 2 counts each
    int2 c = reinterpret_cast<const int2*>(counts)[lane];
    int lsum = c.x + c.y;
    int pre = lsum;
    #pragma unroll
    for (int off = 1; off < 64; off <<= 1) {
        int v = __shfl_up(pre, off);
        if (lane >= off) pre += v;
    }
    int excl = pre - lsum;
    int2 outv = make_int2(excl, excl + c.x);
    reinterpret_cast<int2*>(starts)[lane] = outv;
    reinterpret_cast<int2*>(cursor)[lane] = outv;
    if (lane == 63) starts[128] = excl + c.x + c.y;
}

__global__ void prep_scatter(const int* __restrict__ rr, const int* __restrict__ cc,
                             const int* __restrict__ seg, int n, int* cursor,
                             int* b_pos, int* b_seg) {
    int i = blockIdx.x * 256 + threadIdx.x;
    if (i < n) {
        int c = cc[i], r = rr[i];
        if (keep_point(r, c)) {
            int j = (int)(bitrev8((unsigned)c) >> 1);
            int pos = atomicAdd(&cursor[j], 1);
            b_pos[pos] = (int)bitrev8((unsigned)r);
            b_seg[pos] = seg[i];
        }
    }
}

// ---------------------------------------------------------------------------
// Row-pass FFT: one row per wave, no LDS, no barriers. Stores only the
// odd-e outputs (frequencies v>=128) compacted: G[img][x][e>>1], e odd.
// ---------------------------------------------------------------------------
__global__ __launch_bounds__(1024) void rowfft_kernel(
    const float* __restrict__ inp, const float* __restrict__ tgt,
    float2* __restrict__ G, int pair_base)
{
    int bid  = blockIdx.x;
    int limg = bid >> 4;                          // 16 blocks per image
    int wv   = threadIdx.x >> 6;
    int lane = threadIdx.x & 63;
    int row  = ((bid & 15) << 4) + wv;
    int t    = limg & 1;
    int p    = pair_base + (limg >> 1);
    const float* src = (t == 0 ? inp : tgt) + (((size_t)p) << 16) + ((size_t)row << 8);

    float2 x[4];
    #pragma unroll
    for (int i = 0; i < 4; i++) x[i] = make_float2(src[i * 64 + lane], 0.f);

    fft256(x, lane);

    float2* dst = G + (((size_t)limg) << 15) + ((size_t)row << 7);  // 256*128 per img
    if (lane & 1) {
        #pragma unroll
        for (int i = 0; i < 4; i++) dst[i * 32 + (lane >> 1)] = x[i];
    }
}

// ---------------------------------------------------------------------------
// Column-pass FFT (register) fused with gather+segment-accumulate.
// 1024 threads = 16 waves; block = one pair x 16 stored columns.
// LDS: coalescing tile (aliased afterwards as per-wave F buffers) + accl.
// ---------------------------------------------------------------------------
#define TP 17   // tile pad (float2 per x-row)
__global__ __launch_bounds__(1024) void colfft_gather_kernel(
    const float2* __restrict__ G, const int* __restrict__ starts,
    const int* __restrict__ b_pos, const int* __restrict__ b_seg,
    float* __restrict__ acc)
{
    __shared__ float2 tile[2 * 256 * TP];        // 69632 B, reused as F buffers
    __shared__ float accl[NSEG * 3];
    int tid  = threadIdx.x;
    int wv   = tid >> 6;
    int lane = tid & 63;
    int plocal = blockIdx.x >> 3;
    int cg     = blockIdx.x & 7;
    int j0     = cg << 4;

    for (int i = tid; i < NSEG * 3; i += 1024) accl[i] = 0.f;

    const float2* Gp = G + (((size_t)plocal) << 16);   // 2 images * 32768

    // coalesced tile load: 2 img x 256 x x 16 cols
    #pragma unroll
    for (int k = 0; k < 8; k++) {
        int idx = tid + (k << 10);               // 0..8191
        int img = idx >> 12;
        int x   = (idx >> 4) & 255;
        int c   = idx & 15;
        tile[img * (256 * TP) + x * TP + c] =
            Gp[((size_t)img << 15) + (x << 7) + j0 + c];
    }
    __syncthreads();

    // each wave reads its own column (bank-friendly: stride 17 float2)
    float2 x1[4], x2[4];
    #pragma unroll
    for (int i = 0; i < 4; i++) {
        int xx = i * 64 + lane;
        x1[i] = tile[xx * TP + wv];
        x2[i] = tile[256 * TP + xx * TP + wv];
    }
    __syncthreads();                             // tile fully consumed

    fft256(x1, lane);
    fft256(x2, lane);

    // per-wave F buffers aliased over the tile
    float2* F1 = tile + wv * 512;
    float2* F2 = F1 + 256;
    #pragma unroll
    for (int i = 0; i < 4; i++) {
        F1[i * 64 + lane] = x1[i];
        F2[i * 64 + lane] = x2[i];
    }
    __syncthreads();

    // gather this wave's column points
    int col = j0 + wv;
    int s0 = starts[col], s1 = starts[col + 1];
    for (int e = s0 + lane; e < s1; e += 64) {
        int pos = b_pos[e];
        int sg  = b_seg[e];
        float2 f1 = F1[pos];
        float2 f2 = F2[pos];
        atomicAdd(&accl[sg * 3 + 0], f1.x * f2.x + f1.y * f2.y);  // Re(F1*conj(F2))
        atomicAdd(&accl[sg * 3 + 1], f1.x * f1.x + f1.y * f1.y);
        atomicAdd(&accl[sg * 3 + 2], f2.x * f2.x + f2.y * f2.y);
    }
    __syncthreads();

    for (int i = tid; i < NSEG * 3; i += 1024) {
        float v = accl[i];
        if (v != 0.f) atomicAdd(&acc[i], v);
    }
}

// ---------------------------------------------------------------------------
// curve_s = |ReS_c| / sqrt(S1*S2); out = npairs * (w[0] + sum curve_s * w[s+1])
// ---------------------------------------------------------------------------
__global__ void final_kernel(const float* __restrict__ acc, const float* __restrict__ w,
                             float* __restrict__ out, float scale) {
    int lane = threadIdx.x;                       // 64 threads
    float val = 0.f;
    for (int s = lane; s < NSEG; s += 64) {
        float cr = acc[s * 3 + 0];
        float p1 = acc[s * 3 + 1];
        float p2 = acc[s * 3 + 2];
        float den = p1 * p2;
        float curve = den > 0.f ? fabsf(cr) * rsqrtf(den) : 0.f;
        val += curve * w[s + 1];
    }
    if (lane == 0) val += w[0];                   // curve[0] = 1
    #pragma unroll
    for (int off = 32; off > 0; off >>= 1) val += __shfl_down(val, off);
    if (lane == 0) out[0] = scale * val;
}

// ---------------------------------------------------------------------------
extern "C" void kernel_launch(void* const* d_in, const int* in_sizes, int n_in,
                              void* d_out, int out_size, void* d_ws, size_t ws_size,
                              hipStream_t stream)
{
    const float* inp = (const float*)d_in[0];
    const float* tgt = (const float*)d_in[1];
    const float* wts = (const float*)d_in[2];
    const int*   rr  = (const int*)d_in[3];
    const int*   cc  = (const int*)d_in[4];
    const int*   sg  = (const int*)d_in[5];
    int npts   = in_sizes[3];
    int npairs = in_sizes[0] >> 16;               // B*C (65536 px/img)

    char* ws = (char*)d_ws;
    float* acc    = (float*)(ws + 0);             // 378 floats
    int*   counts = (int*)(ws + 2048);            // 128 ints
    int*   starts = (int*)(ws + 2560);            // 129 ints
    int*   cursor = (int*)(ws + 3584);            // 128 ints
    int*   b_pos  = (int*)(ws + 4096);
    int*   b_seg  = b_pos + npts;
    size_t goff = 4096 + (size_t)2 * npts * 4;
    goff = (goff + 255) & ~(size_t)255;
    float2* G = (float2*)(ws + goff);

    size_t per_pair = (size_t)2 * 256 * 128 * sizeof(float2);   // 512 KiB
    int maxchunk = (int)((ws_size > goff ? (ws_size - goff) : 0) / per_pair);
    if (maxchunk < 1) maxchunk = 1;
    if (maxchunk > npairs) maxchunk = npairs;

    prep_zero<<<2, 256, 0, stream>>>(acc, counts);
    prep_hist<<<(npts + 255) / 256, 256, 0, stream>>>(rr, cc, npts, counts);
    prep_scan<<<1, 64, 0, stream>>>(counts, starts, cursor);
    prep_scatter<<<(npts + 255) / 256, 256, 0, stream>>>(rr, cc, sg, npts, cursor, b_pos, b_seg);

    for (int pb = 0; pb < npairs; pb += maxchunk) {
        int cp = npairs - pb < maxchunk ? npairs - pb : maxchunk;
        rowfft_kernel<<<cp * 32, 1024, 0, stream>>>(inp, tgt, G, pb);
        colfft_gather_kernel<<<cp * 8, 1024, 0, stream>>>(G, starts, b_pos, b_seg, acc);
    }

    final_kernel<<<1, 64, 0, stream>>>(acc, wts, (float*)d_out, (float)npairs);
}